// Round 1
// baseline (2325.748 us; speedup 1.0000x reference)
//
#include <hip/hip_runtime.h>
#include <math.h>

#define NTHREADS 256

// ---------------------------------------------------------------------------
// Tiled GEMM layer: out[c][t] = act( bias[c] + sum_k inT[k][t] * W[k][c] )
//   inT : smem, [K][32] feature-major (stride 32 floats)
//   outT: smem, [128][32]
//   W   : global, [K][128] row-major
//   256 threads: cg = (tid&31)*4 (column group), ng = (tid>>5)*4 (tile-row grp)
//   4x4 register blocking: 16 FMA per (1x ds_read_b128 weights + 1x b128 acts)
// ---------------------------------------------------------------------------
__device__ __forceinline__ void gemm_layer(const float* inT, float* outT,
                                           const float* __restrict__ W,
                                           const float* __restrict__ bias,
                                           float* wbuf, int K, int tid, bool relu)
{
    const int cg = (tid & 31) << 2;
    const int ng = (tid >> 5) << 2;
    float4 bv = *reinterpret_cast<const float4*>(&bias[cg]);
    float acc[4][4];
#pragma unroll
    for (int i = 0; i < 4; ++i) {
        acc[i][0] = bv.x; acc[i][1] = bv.y; acc[i][2] = bv.z; acc[i][3] = bv.w;
    }
    for (int kc = 0; kc < K; kc += 64) {
        const int CS = min(64, K - kc);
        // stage weight chunk [CS][128] (coalesced)
        for (int idx = tid; idx < (CS << 7); idx += NTHREADS)
            wbuf[idx] = W[((size_t)(kc + (idx >> 7)) << 7) + (idx & 127)];
        __syncthreads();
        for (int k = 0; k < CS; ++k) {
            float4 wv = *reinterpret_cast<const float4*>(&wbuf[(k << 7) + cg]);
            float4 xv = *reinterpret_cast<const float4*>(&inT[((kc + k) << 5) + ng]);
            acc[0][0] = fmaf(xv.x, wv.x, acc[0][0]);
            acc[0][1] = fmaf(xv.x, wv.y, acc[0][1]);
            acc[0][2] = fmaf(xv.x, wv.z, acc[0][2]);
            acc[0][3] = fmaf(xv.x, wv.w, acc[0][3]);
            acc[1][0] = fmaf(xv.y, wv.x, acc[1][0]);
            acc[1][1] = fmaf(xv.y, wv.y, acc[1][1]);
            acc[1][2] = fmaf(xv.y, wv.z, acc[1][2]);
            acc[1][3] = fmaf(xv.y, wv.w, acc[1][3]);
            acc[2][0] = fmaf(xv.z, wv.x, acc[2][0]);
            acc[2][1] = fmaf(xv.z, wv.y, acc[2][1]);
            acc[2][2] = fmaf(xv.z, wv.z, acc[2][2]);
            acc[2][3] = fmaf(xv.z, wv.w, acc[2][3]);
            acc[3][0] = fmaf(xv.w, wv.x, acc[3][0]);
            acc[3][1] = fmaf(xv.w, wv.y, acc[3][1]);
            acc[3][2] = fmaf(xv.w, wv.z, acc[3][2]);
            acc[3][3] = fmaf(xv.w, wv.w, acc[3][3]);
        }
        __syncthreads();
    }
#pragma unroll
    for (int j = 0; j < 4; ++j) {
#pragma unroll
        for (int i = 0; i < 4; ++i) {
            float v = acc[i][j];
            if (relu) v = fmaxf(v, 0.0f);
            outT[((cg + j) << 5) + ng + i] = v;
        }
    }
    __syncthreads();
}

// ---------------------------------------------------------------------------
// root encoder: root_emb = relu(root_repr @ W_root + b_root)   [2000 x 128]
// ---------------------------------------------------------------------------
__global__ void root_kernel(const float* __restrict__ root_repr,
                            const float* __restrict__ W_root,
                            const float* __restrict__ b_root,
                            float* __restrict__ root_emb)
{
    __shared__ float x[86];
    const int r = blockIdx.x;
    const int tid = threadIdx.x;  // 128
    if (tid < 86) x[tid] = root_repr[(size_t)r * 86 + tid];
    __syncthreads();
    float acc = b_root[tid];
    for (int k = 0; k < 86; ++k)
        acc = fmaf(x[k], W_root[k * 128 + tid], acc);
    root_emb[(size_t)r * 128 + tid] = fmaxf(acc, 0.0f);
}

// ---------------------------------------------------------------------------
// node pipeline: h2 = relu(relu((x@W_in+b)@W_g1+b)@W_g2+b) fused, 32 nodes/blk
// then run-length segment accumulation (segment_ids are sorted)
// ---------------------------------------------------------------------------
__global__ __launch_bounds__(256, 2)
void node_kernel(const float* __restrict__ node_h, const int* __restrict__ seg_ids,
                 const float* __restrict__ W_in, const float* __restrict__ b_in,
                 const float* __restrict__ W_g1, const float* __restrict__ b_g1,
                 const float* __restrict__ W_g2, const float* __restrict__ b_g2,
                 float* __restrict__ frag_sum, float* __restrict__ frag_cnt)
{
    __shared__ __align__(16) float bufA[128 * 32];
    __shared__ __align__(16) float bufB[128 * 32];
    __shared__ __align__(16) float wbuf[64 * 128];
    __shared__ int segs[32];
    const int tid = threadIdx.x;
    const long n0 = (long)blockIdx.x * 32;

    if (tid < 32) {
        int s = seg_ids[n0 + tid];
        segs[tid] = s;
        atomicAdd(&frag_cnt[s], 1.0f);
    }
    // stage node_h tile transposed: bufA[k*32+n] = node_h[(n0+n)*86+k]
    for (int idx = tid; idx < 86 * 32; idx += NTHREADS) {
        int n = idx / 86, k = idx - n * 86;
        bufA[k * 32 + n] = node_h[(n0 + n) * 86 + k];
    }
    __syncthreads();

    gemm_layer(bufA, bufB, W_in, b_in, wbuf, 86, tid, false);  // no relu!
    gemm_layer(bufB, bufA, W_g1, b_g1, wbuf, 128, tid, true);
    gemm_layer(bufA, bufB, W_g2, b_g2, wbuf, 128, tid, true);

    // segment-sum: bufB[c*32+n], sorted segs -> run-flush (few atomics/col)
    if (tid < 128) {
        const int c = tid;
        int cur = segs[0];
        float run = 0.0f;
        for (int n = 0; n < 32; ++n) {
            int s = segs[n];
            if (s != cur) {
                atomicAdd(&frag_sum[(size_t)cur * 128 + c], run);
                run = 0.0f; cur = s;
            }
            run += bufB[c * 32 + n];
        }
        atomicAdd(&frag_sum[(size_t)cur * 128 + c], run);
    }
}

// ---------------------------------------------------------------------------
// fragment MLP + heads, 32 fragments per block
// ---------------------------------------------------------------------------
__global__ __launch_bounds__(256, 1)
void frag_kernel(const float* __restrict__ root_emb, const float* __restrict__ frag_sum,
                 const float* __restrict__ frag_cnt, const int* __restrict__ ind_maps,
                 const int* __restrict__ broken,
                 const float* __restrict__ W_m1, const float* __restrict__ b_m1,
                 const float* __restrict__ W_m2, const float* __restrict__ b_m2,
                 const float* __restrict__ W_out, const float* __restrict__ b_out,
                 const float* __restrict__ W_attn, const float* __restrict__ b_attn,
                 float* __restrict__ out0, float* __restrict__ out1)
{
    __shared__ __align__(16) float catT[397 * 32];   // also reused for h2
    __shared__ __align__(16) float h1T[128 * 32];
    __shared__ __align__(16) float wbuf[64 * 128];
    __shared__ float invc[32];
    const int tid = threadIdx.x;
    const long f0 = (long)blockIdx.x * 32;

    if (tid < 32) {
        float c = frag_cnt[f0 + tid];
        invc[tid] = 1.0f / fmaxf(c, 1.0f);
        int b = broken[f0 + tid];
        b = min(max(b, 0), 12);
        for (int j = 0; j < 13; ++j)
            catT[(384 + j) * 32 + tid] = (j == b) ? 1.0f : 0.0f;
    }
    __syncthreads();
    {
        const int fr = tid >> 3;            // 0..31
        const int kq = (tid & 7) << 4;      // 0,16,...,112
        const int rid = ind_maps[f0 + fr];
        const float inv = invc[fr];
        for (int k = kq; k < kq + 16; ++k) {
            float e = root_emb[(size_t)rid * 128 + k];
            float s = frag_sum[(size_t)(f0 + fr) * 128 + k] * inv;
            catT[k * 32 + fr] = e;
            catT[(128 + k) * 32 + fr] = e - s;
            catT[(256 + k) * 32 + fr] = s;
        }
    }
    __syncthreads();

    gemm_layer(catT, h1T, W_m1, b_m1, wbuf, 397, tid, true);
    gemm_layer(h1T, catT, W_m2, b_m2, wbuf, 128, tid, true);  // h2 -> catT

    // heads: 26 outputs x 32 frags, K=128
    const float* h2 = catT;
    const int fr = tid & 31;
#pragma unroll
    for (int p = 0; p < 4; ++p) {
        int jj = (tid >> 5) + (p << 3);
        if (jj < 26) {
            const bool is_out = (jj < 13);
            const int j = is_out ? jj : jj - 13;
            const float* Wh = is_out ? W_out : W_attn;
            float acc = is_out ? b_out[j] : b_attn[j];
            for (int k = 0; k < 128; ++k)
                acc = fmaf(h2[k * 32 + fr], Wh[k * 13 + j], acc);
            if (is_out) {
                acc = 1.0f / (1.0f + expf(-acc));
                out0[(f0 + fr) * 13 + j] = acc;
            } else {
                out1[(f0 + fr) * 13 + j] = acc;
            }
        }
    }
}

extern "C" void kernel_launch(void* const* d_in, const int* in_sizes, int n_in,
                              void* d_out, int out_size, void* d_ws, size_t ws_size,
                              hipStream_t stream)
{
    const float* node_h    = (const float*)d_in[0];
    const int*   seg_ids   = (const int*)d_in[1];
    const float* root_repr = (const float*)d_in[2];
    const int*   ind_maps  = (const int*)d_in[3];
    const int*   broken    = (const int*)d_in[4];
    const float* W_root = (const float*)d_in[5];  const float* b_root = (const float*)d_in[6];
    const float* W_in   = (const float*)d_in[7];  const float* b_in   = (const float*)d_in[8];
    const float* W_g1   = (const float*)d_in[9];  const float* b_g1   = (const float*)d_in[10];
    const float* W_g2   = (const float*)d_in[11]; const float* b_g2   = (const float*)d_in[12];
    const float* W_m1   = (const float*)d_in[13]; const float* b_m1   = (const float*)d_in[14];
    const float* W_m2   = (const float*)d_in[15]; const float* b_m2   = (const float*)d_in[16];
    const float* W_out  = (const float*)d_in[17]; const float* b_out  = (const float*)d_in[18];
    const float* W_attn = (const float*)d_in[19]; const float* b_attn = (const float*)d_in[20];

    float* ws = (float*)d_ws;
    float* root_emb = ws;                                  // 2000*128
    float* frag_sum = ws + 2000 * 128;                     // 100000*128
    float* frag_cnt = frag_sum + (size_t)100000 * 128;     // 100000
    hipMemsetAsync(frag_sum, 0,
                   ((size_t)100000 * 128 + 100000) * sizeof(float), stream);

    float* out0 = (float*)d_out;
    float* out1 = out0 + (size_t)100000 * 13;

    root_kernel<<<2000, 128, 0, stream>>>(root_repr, W_root, b_root, root_emb);
    node_kernel<<<25000, 256, 0, stream>>>(node_h, seg_ids, W_in, b_in,
                                           W_g1, b_g1, W_g2, b_g2,
                                           frag_sum, frag_cnt);
    frag_kernel<<<3125, 256, 0, stream>>>(root_emb, frag_sum, frag_cnt,
                                          ind_maps, broken,
                                          W_m1, b_m1, W_m2, b_m2,
                                          W_out, b_out, W_attn, b_attn,
                                          out0, out1);
}

// Round 2
// 729.442 us; speedup vs baseline: 3.1884x; 3.1884x over previous
//
#include <hip/hip_runtime.h>
#include <math.h>

typedef __attribute__((ext_vector_type(8))) short short8;
typedef __attribute__((ext_vector_type(4))) float float4v;

__device__ __forceinline__ unsigned short f2bf(float f) {
    union { float f; unsigned u; } v; v.f = f;
    return (unsigned short)((v.u + 0x7fffu + ((v.u >> 16) & 1u)) >> 16);
}

// ---------------------------------------------------------------------------
// MFMA GEMM: 64 rows x 128 cols, acts [64][astr] bf16 LDS, WT [128][KP] bf16
// global (row n holds W^T[n][k] = W[k][n]).  4 waves: wave w -> rows 16w..+15,
// each wave does all 8 col-tiles of 16.  A-frag: A[m=lane&15][k=q*8+j].
// B-frag: B[k=q*8+j][n=lane&15] read from WT[n][k] (contiguous 16B).
// ---------------------------------------------------------------------------
template<int KP>
__device__ __forceinline__ void mfma_gemm(const unsigned short* acts, int astr,
                                          const unsigned short* __restrict__ WT,
                                          const float* __restrict__ bias,
                                          unsigned short* wbuf, int tid,
                                          float4v acc[8])
{
    const int lane = tid & 63, w = tid >> 6, col0 = lane & 15, q = lane >> 4;
#pragma unroll
    for (int t = 0; t < 8; ++t) {
        float b = bias[t * 16 + col0];
        acc[t] = (float4v){b, b, b, b};
    }
    const unsigned short* arow = acts + (w * 16 + col0) * astr + q * 8;
    for (int kc = 0; kc < KP; kc += 64) {
        const int CS = (KP - kc) < 64 ? (KP - kc) : 64;
        __syncthreads();
        const int tpr = CS >> 3;  // float4 (8 bf16) copies per WT row
        for (int it = tid; it < 128 * tpr; it += 256) {
            int c = it / tpr, kk = (it - c * tpr) << 3;
            *(float4*)(wbuf + c * 72 + kk) =
                *(const float4*)(WT + (size_t)c * KP + kc + kk);
        }
        __syncthreads();
        for (int ks = 0; ks < CS; ks += 32) {
            short8 a = *(const short8*)(arow + kc + ks);
#pragma unroll
            for (int t = 0; t < 8; ++t) {
                short8 b = *(const short8*)(wbuf + (t * 16 + col0) * 72 + ks + q * 8);
                acc[t] = __builtin_amdgcn_mfma_f32_16x16x32_bf16(a, b, acc[t], 0, 0, 0);
            }
        }
    }
}

// C/D layout: col = lane&15 (+16t), row = q*4 + reg (+16w)
__device__ __forceinline__ void store_bf16(const float4v acc[8], unsigned short* out,
                                           int ostr, int tid, bool relu)
{
    const int lane = tid & 63, w = tid >> 6, col0 = lane & 15, q = lane >> 4;
#pragma unroll
    for (int t = 0; t < 8; ++t)
#pragma unroll
        for (int r = 0; r < 4; ++r) {
            float v = acc[t][r];
            if (relu) v = fmaxf(v, 0.0f);
            out[(w * 16 + q * 4 + r) * ostr + t * 16 + col0] = f2bf(v);
        }
}

// ---------------------------------------------------------------------------
// weight prep: fp32 [K][128] -> bf16 transposed [128][KP] (zero k-padding)
// ---------------------------------------------------------------------------
__global__ void prep_kernel(const float* __restrict__ W_in, const float* __restrict__ W_g1,
                            const float* __restrict__ W_g2, const float* __restrict__ W_m1,
                            const float* __restrict__ W_m2, const float* __restrict__ W_out,
                            const float* __restrict__ W_attn, unsigned short* __restrict__ wt)
{
    int i = blockIdx.x * 256 + threadIdx.x;
    unsigned short* WT_in = wt;                 // [128][96]
    unsigned short* WT_g1 = WT_in + 12288;      // [128][128]
    unsigned short* WT_g2 = WT_g1 + 16384;      // [128][128]
    unsigned short* WT_m1 = WT_g2 + 16384;      // [128][416]
    unsigned short* WT_m2 = WT_m1 + 53248;      // [128][128]
    unsigned short* WT_h  = WT_m2 + 16384;      // [32][128]
    if (i < 12288) { int n = i / 96, k = i - n * 96;
        WT_in[i] = (k < 86) ? f2bf(W_in[k * 128 + n]) : 0; return; }
    i -= 12288;
    if (i < 16384) { int n = i >> 7, k = i & 127;
        WT_g1[i] = f2bf(W_g1[k * 128 + n]); return; }
    i -= 16384;
    if (i < 16384) { int n = i >> 7, k = i & 127;
        WT_g2[i] = f2bf(W_g2[k * 128 + n]); return; }
    i -= 16384;
    if (i < 53248) { int n = i / 416, k = i - n * 416;
        WT_m1[i] = (k < 397) ? f2bf(W_m1[k * 128 + n]) : 0; return; }
    i -= 53248;
    if (i < 16384) { int n = i >> 7, k = i & 127;
        WT_m2[i] = f2bf(W_m2[k * 128 + n]); return; }
    i -= 16384;
    if (i < 4096) { int n = i >> 7, k = i & 127;
        WT_h[i] = (n < 13) ? f2bf(W_out[k * 13 + n])
                           : (n < 26 ? f2bf(W_attn[k * 13 + (n - 13)]) : 0); }
}

// ---------------------------------------------------------------------------
// root encoder (fp32, tiny)
// ---------------------------------------------------------------------------
__global__ void root_kernel(const float* __restrict__ root_repr,
                            const float* __restrict__ W_root,
                            const float* __restrict__ b_root,
                            float* __restrict__ root_emb)
{
    __shared__ float x[86];
    const int r = blockIdx.x, tid = threadIdx.x;  // 128
    if (tid < 86) x[tid] = root_repr[(size_t)r * 86 + tid];
    __syncthreads();
    float acc = b_root[tid];
    for (int k = 0; k < 86; ++k)
        acc = fmaf(x[k], W_root[k * 128 + tid], acc);
    root_emb[(size_t)r * 128 + tid] = fmaxf(acc, 0.0f);
}

// ---------------------------------------------------------------------------
// node pipeline: 64 nodes/block, 3 MFMA layers, then sorted-run segment sum
// LDS: wbuf[0,18432) | P1[18432,35840) | P0[35840,53248)
//      finalF fp32 [64][129] overlays [0,33024) (wbuf+P1, both dead)
// ---------------------------------------------------------------------------
__global__ __launch_bounds__(256, 3)
void node_kernel(const float* __restrict__ node_h, const int* __restrict__ seg_ids,
                 const unsigned short* __restrict__ WT_in, const float* __restrict__ b_in,
                 const unsigned short* __restrict__ WT_g1, const float* __restrict__ b_g1,
                 const unsigned short* __restrict__ WT_g2, const float* __restrict__ b_g2,
                 float* __restrict__ frag_sum, float* __restrict__ frag_cnt)
{
    __shared__ __align__(16) unsigned char smem[53248];
    __shared__ int segs[64];
    unsigned short* wbuf = (unsigned short*)smem;
    unsigned short* P1   = (unsigned short*)(smem + 18432);  // [64][136]
    unsigned short* P0   = (unsigned short*)(smem + 35840);  // [64][136] / [64][104]
    float* finalF = (float*)smem;                            // [64][129]

    const int tid = threadIdx.x;
    const long n0 = (long)blockIdx.x * 64;

    if (tid < 64) {
        int s = seg_ids[n0 + tid];
        segs[tid] = s;
        atomicAdd(&frag_cnt[s], 1.0f);
    }
    for (int idx = tid; idx < 64 * 86; idx += 256) {
        int n = idx / 86, k = idx - n * 86;
        P0[n * 104 + k] = f2bf(node_h[(n0 + n) * 86 + k]);
    }
    for (int idx = tid; idx < 64 * 10; idx += 256) {
        int n = idx / 10, k = idx - n * 10;
        P0[n * 104 + 86 + k] = 0;
    }
    float4v acc[8];
    mfma_gemm<96>(P0, 104, WT_in, b_in, wbuf, tid, acc);   // layer 1: NO relu
    store_bf16(acc, P1, 136, tid, false);
    mfma_gemm<128>(P1, 136, WT_g1, b_g1, wbuf, tid, acc);
    store_bf16(acc, P0, 136, tid, true);
    mfma_gemm<128>(P0, 136, WT_g2, b_g2, wbuf, tid, acc);
    __syncthreads();   // wbuf/P1 reads done before finalF overlay
    {
        const int lane = tid & 63, w = tid >> 6, col0 = lane & 15, q = lane >> 4;
#pragma unroll
        for (int t = 0; t < 8; ++t)
#pragma unroll
            for (int r = 0; r < 4; ++r)
                finalF[(w * 16 + q * 4 + r) * 129 + t * 16 + col0] = fmaxf(acc[t][r], 0.0f);
    }
    __syncthreads();
    {
        const int c = tid & 127, r0 = (tid >> 7) * 32;
        int cur = segs[r0];
        float run = 0.0f;
        for (int n = r0; n < r0 + 32; ++n) {
            int s = segs[n];
            if (s != cur) {
                atomicAdd(&frag_sum[(size_t)cur * 128 + c], run);
                run = 0.0f; cur = s;
            }
            run += finalF[n * 129 + c];
        }
        atomicAdd(&frag_sum[(size_t)cur * 128 + c], run);
    }
}

// ---------------------------------------------------------------------------
// fragment MLP + heads: 64 frags/block; cat built on the fly from global
// ---------------------------------------------------------------------------
__global__ __launch_bounds__(256, 3)
void frag_kernel(const float* __restrict__ root_emb, const float* __restrict__ frag_sum,
                 const float* __restrict__ frag_cnt, const int* __restrict__ ind_maps,
                 const int* __restrict__ broken,
                 const unsigned short* __restrict__ WT_m1, const float* __restrict__ b_m1,
                 const unsigned short* __restrict__ WT_m2, const float* __restrict__ b_m2,
                 const unsigned short* __restrict__ WT_h,
                 const float* __restrict__ b_out, const float* __restrict__ b_attn,
                 float* __restrict__ out0, float* __restrict__ out1)
{
    __shared__ __align__(16) unsigned char smem[53248];
    unsigned short* wbuf = (unsigned short*)smem;
    unsigned short* h1 = (unsigned short*)(smem + 18432);   // [64][136]
    unsigned short* h2 = (unsigned short*)(smem + 35840);   // [64][136]
    const int tid = threadIdx.x;
    const int lane = tid & 63, w = tid >> 6, col0 = lane & 15, q = lane >> 4;
    const long f0 = (long)blockIdx.x * 64;
    const int m = w * 16 + col0;
    int fc = (int)(f0 + m); if (fc > 99999) fc = 99999;
    const int rid = ind_maps[fc];
    const float inv = 1.0f / fmaxf(frag_cnt[fc], 1.0f);
    int bi = broken[fc]; bi = bi < 0 ? 0 : (bi > 12 ? 12 : bi);

    float4v acc[8];
#pragma unroll
    for (int t = 0; t < 8; ++t) {
        float b = b_m1[t * 16 + col0];
        acc[t] = (float4v){b, b, b, b};
    }
    for (int kc = 0; kc < 416; kc += 64) {
        const int CS = (416 - kc) < 64 ? (416 - kc) : 64;
        __syncthreads();
        const int tpr = CS >> 3;
        for (int it = tid; it < 128 * tpr; it += 256) {
            int c = it / tpr, kk = (it - c * tpr) << 3;
            *(float4*)(wbuf + c * 72 + kk) =
                *(const float4*)(WT_m1 + (size_t)c * 416 + kc + kk);
        }
        __syncthreads();
        for (int ks = 0; ks < CS; ks += 32) {
            const int k0 = kc + ks + q * 8;
            float av[8];
            if (k0 >= 384) {
#pragma unroll
                for (int i = 0; i < 8; ++i) {
                    int k = k0 + i;
                    av[i] = (k < 397 && (k - 384) == bi) ? 1.0f : 0.0f;
                }
            } else if (k0 < 128) {
                const float4* e = (const float4*)(root_emb + (size_t)rid * 128 + k0);
                float4 e0 = e[0], e1 = e[1];
                av[0] = e0.x; av[1] = e0.y; av[2] = e0.z; av[3] = e0.w;
                av[4] = e1.x; av[5] = e1.y; av[6] = e1.z; av[7] = e1.w;
            } else if (k0 < 256) {
                int kk = k0 - 128;
                const float4* e = (const float4*)(root_emb + (size_t)rid * 128 + kk);
                const float4* s = (const float4*)(frag_sum + (size_t)fc * 128 + kk);
                float4 e0 = e[0], e1 = e[1], s0 = s[0], s1 = s[1];
                av[0] = e0.x - s0.x * inv; av[1] = e0.y - s0.y * inv;
                av[2] = e0.z - s0.z * inv; av[3] = e0.w - s0.w * inv;
                av[4] = e1.x - s1.x * inv; av[5] = e1.y - s1.y * inv;
                av[6] = e1.z - s1.z * inv; av[7] = e1.w - s1.w * inv;
            } else {
                int kk = k0 - 256;
                const float4* s = (const float4*)(frag_sum + (size_t)fc * 128 + kk);
                float4 s0 = s[0], s1 = s[1];
                av[0] = s0.x * inv; av[1] = s0.y * inv; av[2] = s0.z * inv; av[3] = s0.w * inv;
                av[4] = s1.x * inv; av[5] = s1.y * inv; av[6] = s1.z * inv; av[7] = s1.w * inv;
            }
            short8 a;
#pragma unroll
            for (int i = 0; i < 8; ++i) a[i] = (short)f2bf(av[i]);
#pragma unroll
            for (int t = 0; t < 8; ++t) {
                short8 b = *(const short8*)(wbuf + (t * 16 + col0) * 72 + ks + q * 8);
                acc[t] = __builtin_amdgcn_mfma_f32_16x16x32_bf16(a, b, acc[t], 0, 0, 0);
            }
        }
    }
    store_bf16(acc, h1, 136, tid, true);
    mfma_gemm<128>(h1, 136, WT_m2, b_m2, wbuf, tid, acc);
    store_bf16(acc, h2, 136, tid, true);
    __syncthreads();
    // heads: 2 col-tiles (26 valid cols), K=128, B direct from global (L1/L2-hot)
    float4v hacc[2];
#pragma unroll
    for (int t = 0; t < 2; ++t) {
        int cc = t * 16 + col0;
        float b = cc < 13 ? b_out[cc] : (cc < 26 ? b_attn[cc - 13] : 0.0f);
        hacc[t] = (float4v){b, b, b, b};
    }
#pragma unroll
    for (int ks = 0; ks < 128; ks += 32) {
        short8 a = *(const short8*)(h2 + m * 136 + ks + q * 8);
#pragma unroll
        for (int t = 0; t < 2; ++t) {
            short8 b = *(const short8*)(WT_h + (t * 16 + col0) * 128 + ks + q * 8);
            hacc[t] = __builtin_amdgcn_mfma_f32_16x16x32_bf16(a, b, hacc[t], 0, 0, 0);
        }
    }
#pragma unroll
    for (int t = 0; t < 2; ++t)
#pragma unroll
        for (int r = 0; r < 4; ++r) {
            long ff = f0 + w * 16 + q * 4 + r;
            if (ff < 100000) {
                int cc = t * 16 + col0;
                float v = hacc[t][r];
                if (cc < 13)      out0[ff * 13 + cc] = 1.0f / (1.0f + expf(-v));
                else if (cc < 26) out1[ff * 13 + cc - 13] = v;
            }
        }
}

extern "C" void kernel_launch(void* const* d_in, const int* in_sizes, int n_in,
                              void* d_out, int out_size, void* d_ws, size_t ws_size,
                              hipStream_t stream)
{
    const float* node_h    = (const float*)d_in[0];
    const int*   seg_ids   = (const int*)d_in[1];
    const float* root_repr = (const float*)d_in[2];
    const int*   ind_maps  = (const int*)d_in[3];
    const int*   broken    = (const int*)d_in[4];
    const float* W_root = (const float*)d_in[5];  const float* b_root = (const float*)d_in[6];
    const float* W_in   = (const float*)d_in[7];  const float* b_in   = (const float*)d_in[8];
    const float* W_g1   = (const float*)d_in[9];  const float* b_g1   = (const float*)d_in[10];
    const float* W_g2   = (const float*)d_in[11]; const float* b_g2   = (const float*)d_in[12];
    const float* W_m1   = (const float*)d_in[13]; const float* b_m1   = (const float*)d_in[14];
    const float* W_m2   = (const float*)d_in[15]; const float* b_m2   = (const float*)d_in[16];
    const float* W_out  = (const float*)d_in[17]; const float* b_out  = (const float*)d_in[18];
    const float* W_attn = (const float*)d_in[19]; const float* b_attn = (const float*)d_in[20];

    char* ws = (char*)d_ws;
    float* root_emb = (float*)ws;                          // 2000*128*4   = 1,024,000
    float* frag_sum = (float*)(ws + 1024000);              // 100000*128*4 = 51,200,000
    float* frag_cnt = (float*)(ws + 52224000);             // 100000*4     = 400,000
    unsigned short* wt = (unsigned short*)(ws + 52624000); // bf16 weights, 237,568 B
    const unsigned short* WT_in = wt;
    const unsigned short* WT_g1 = wt + 12288;
    const unsigned short* WT_g2 = WT_g1 + 16384;
    const unsigned short* WT_m1 = WT_g2 + 16384;
    const unsigned short* WT_m2 = WT_m1 + 53248;
    const unsigned short* WT_h  = WT_m2 + 16384;

    hipMemsetAsync(frag_sum, 0, 51600000, stream);  // frag_sum + frag_cnt

    float* out0 = (float*)d_out;
    float* out1 = out0 + (size_t)100000 * 13;

    prep_kernel<<<464, 256, 0, stream>>>(W_in, W_g1, W_g2, W_m1, W_m2, W_out, W_attn, wt);
    root_kernel<<<2000, 128, 0, stream>>>(root_repr, W_root, b_root, root_emb);
    node_kernel<<<12500, 256, 0, stream>>>(node_h, seg_ids, WT_in, b_in,
                                           WT_g1, b_g1, WT_g2, b_g2, frag_sum, frag_cnt);
    frag_kernel<<<1563, 256, 0, stream>>>(root_emb, frag_sum, frag_cnt, ind_maps, broken,
                                          WT_m1, b_m1, WT_m2, b_m2, WT_h, b_out, b_attn,
                                          out0, out1);
}

// Round 3
// 693.596 us; speedup vs baseline: 3.3532x; 1.0517x over previous
//
#include <hip/hip_runtime.h>
#include <math.h>

typedef __attribute__((ext_vector_type(8))) short short8;
typedef __attribute__((ext_vector_type(4))) float float4v;

#define AST 136  // activation row stride in bf16 elements

__device__ __forceinline__ unsigned short f2bf(float f) {
    union { float f; unsigned u; } v; v.f = f;
    return (unsigned short)((v.u + 0x7fffu + ((v.u >> 16) & 1u)) >> 16);
}
__device__ __forceinline__ float bf2f(unsigned v) {
    union { unsigned u; float f; } x; x.u = v << 16; return x.f;
}

// ---------------------------------------------------------------------------
// Per-wave MFMA layer: M=64 rows (4 m-tiles), N=128 (8 n-tiles), K=KP.
// A from wave-private LDS X[row*AST+k]; B straight from global WT[n][k]
// (L2-resident, 16 rows x 64B line-coalesced). Zero barriers.
// ---------------------------------------------------------------------------
template<int KP>
__device__ __forceinline__ void layerN(const unsigned short* X,
                                       const unsigned short* __restrict__ WT,
                                       const float* __restrict__ bias,
                                       int lane, float4v acc[4][8])
{
    const int col0 = lane & 15, q = lane >> 4;
#pragma unroll
    for (int t = 0; t < 8; ++t) {
        float b = bias[t * 16 + col0];
#pragma unroll
        for (int mt = 0; mt < 4; ++mt) acc[mt][t] = (float4v){b, b, b, b};
    }
    for (int ks = 0; ks < KP; ks += 32) {
        const int k0 = ks + q * 8;
        short8 B[8];
#pragma unroll
        for (int t = 0; t < 8; ++t)
            B[t] = *(const short8*)(WT + (size_t)(t * 16 + col0) * KP + k0);
#pragma unroll
        for (int mt = 0; mt < 4; ++mt) {
            short8 A = *(const short8*)(X + (mt * 16 + col0) * AST + k0);
#pragma unroll
            for (int t = 0; t < 8; ++t)
                acc[mt][t] = __builtin_amdgcn_mfma_f32_16x16x32_bf16(A, B[t], acc[mt][t], 0, 0, 0);
        }
    }
}

// C/D layout: col = col0 + 16t, row = 16mt + 4q + r
__device__ __forceinline__ void storeh(float4v acc[4][8], unsigned short* X,
                                       int lane, bool relu)
{
    const int col0 = lane & 15, q = lane >> 4;
#pragma unroll
    for (int mt = 0; mt < 4; ++mt)
#pragma unroll
        for (int t = 0; t < 8; ++t)
#pragma unroll
            for (int r = 0; r < 4; ++r) {
                float v = acc[mt][t][r];
                if (relu) v = fmaxf(v, 0.0f);
                X[(mt * 16 + q * 4 + r) * AST + t * 16 + col0] = f2bf(v);
            }
}

// ---------------------------------------------------------------------------
// weight prep: fp32 [K][128] -> bf16 transposed [128][KP] (zero k-padding)
// ---------------------------------------------------------------------------
__global__ void prep_kernel(const float* __restrict__ W_in, const float* __restrict__ W_g1,
                            const float* __restrict__ W_g2, const float* __restrict__ W_m1,
                            const float* __restrict__ W_m2, const float* __restrict__ W_out,
                            const float* __restrict__ W_attn, unsigned short* __restrict__ wt)
{
    int i = blockIdx.x * 256 + threadIdx.x;
    unsigned short* WT_in = wt;                 // [128][96]
    unsigned short* WT_g1 = WT_in + 12288;      // [128][128]
    unsigned short* WT_g2 = WT_g1 + 16384;      // [128][128]
    unsigned short* WT_m1 = WT_g2 + 16384;      // [128][416]
    unsigned short* WT_m2 = WT_m1 + 53248;      // [128][128]
    unsigned short* WT_h  = WT_m2 + 16384;      // [32][128]
    if (i < 12288) { int n = i / 96, k = i - n * 96;
        WT_in[i] = (k < 86) ? f2bf(W_in[k * 128 + n]) : 0; return; }
    i -= 12288;
    if (i < 16384) { int n = i >> 7, k = i & 127;
        WT_g1[i] = f2bf(W_g1[k * 128 + n]); return; }
    i -= 16384;
    if (i < 16384) { int n = i >> 7, k = i & 127;
        WT_g2[i] = f2bf(W_g2[k * 128 + n]); return; }
    i -= 16384;
    if (i < 53248) { int n = i / 416, k = i - n * 416;
        WT_m1[i] = (k < 397) ? f2bf(W_m1[k * 128 + n]) : 0; return; }
    i -= 53248;
    if (i < 16384) { int n = i >> 7, k = i & 127;
        WT_m2[i] = f2bf(W_m2[k * 128 + n]); return; }
    i -= 16384;
    if (i < 4096) { int n = i >> 7, k = i & 127;
        WT_h[i] = (n < 13) ? f2bf(W_out[k * 13 + n])
                           : (n < 26 ? f2bf(W_attn[k * 13 + (n - 13)]) : 0); }
}

// ---------------------------------------------------------------------------
// root encoder (fp32, tiny)
// ---------------------------------------------------------------------------
__global__ void root_kernel(const float* __restrict__ root_repr,
                            const float* __restrict__ W_root,
                            const float* __restrict__ b_root,
                            float* __restrict__ root_emb)
{
    __shared__ float x[86];
    const int r = blockIdx.x, tid = threadIdx.x;  // 128
    if (tid < 86) x[tid] = root_repr[(size_t)r * 86 + tid];
    __syncthreads();
    float acc = b_root[tid];
    for (int k = 0; k < 86; ++k)
        acc = fmaf(x[k], W_root[k * 128 + tid], acc);
    root_emb[(size_t)r * 128 + tid] = fmaxf(acc, 0.0f);
}

// ---------------------------------------------------------------------------
// node pipeline: one wave per 64-row strip, zero barriers.
// Wave stages x into its private LDS slice, runs 3 MFMA layers (B from
// global), then run-length segment reduction (sorted seg ids) with atomics.
// ---------------------------------------------------------------------------
__global__ __launch_bounds__(512, 2)
void node_kernel(const float* __restrict__ node_h, const int* __restrict__ seg_ids,
                 const unsigned short* __restrict__ WT_in, const float* __restrict__ b_in,
                 const unsigned short* __restrict__ WT_g1, const float* __restrict__ b_g1,
                 const unsigned short* __restrict__ WT_g2, const float* __restrict__ b_g2,
                 float* __restrict__ frag_sum, float* __restrict__ frag_cnt)
{
    __shared__ unsigned short abuf[8 * 64 * AST];   // 139264 B, wave-private slices
    __shared__ int segs[8 * 64];
    const int tid = threadIdx.x, wv = tid >> 6, lane = tid & 63;
    const int strip = blockIdx.x * 8 + wv;
    if (strip >= 12500) return;
    const long n0 = (long)strip * 64;
    unsigned short* X = abuf + wv * (64 * AST);
    int* sg = segs + wv * 64;

    sg[lane] = seg_ids[n0 + lane];

    // stage x: 64 rows x 86 fp32 (fully contiguous 5504 floats) -> bf16 LDS
    {
        const float4* src = (const float4*)(node_h + n0 * 86);
#pragma unroll
        for (int j = 0; j < 22; ++j) {
            int i4 = j * 64 + lane;
            if (i4 < 1376) {
                float4 v = src[i4];
                int e = i4 << 2;
                int n = e / 86, k = e - n * 86;
                // 4 consecutive elements may wrap a row boundary; recompute per elem
                X[n * AST + k] = f2bf(v.x);
                int e1 = e + 1; n = e1 / 86; k = e1 - n * 86; X[n * AST + k] = f2bf(v.y);
                int e2 = e + 2; n = e2 / 86; k = e2 - n * 86; X[n * AST + k] = f2bf(v.z);
                int e3 = e + 3; n = e3 / 86; k = e3 - n * 86; X[n * AST + k] = f2bf(v.w);
            }
        }
#pragma unroll
        for (int j = 0; j < 10; ++j)
            X[lane * AST + 86 + j] = 0;   // zero-pad k=86..95 (row = lane)
    }

    float4v acc[4][8];
    layerN<96>(X, WT_in, b_in, lane, acc);
    storeh(acc, X, lane, false);            // layer 1: NO relu
    layerN<128>(X, WT_g1, b_g1, lane, acc);
    storeh(acc, X, lane, true);
    layerN<128>(X, WT_g2, b_g2, lane, acc);
    storeh(acc, X, lane, true);             // h3 (relu'd) in X

    // wave-private segment reduction: lane handles cols 2*lane, 2*lane+1
    const int c0 = lane << 1;
    float s0 = 0.f, s1 = 0.f, cnt = 0.f;
    int cur = sg[0];
    for (int n = 0; n < 64; ++n) {
        int s = sg[n];                       // LDS broadcast, wave-uniform
        if (s != cur) {
            atomicAdd(&frag_sum[(size_t)cur * 128 + c0], s0);
            atomicAdd(&frag_sum[(size_t)cur * 128 + c0 + 1], s1);
            if (lane == 0) atomicAdd(&frag_cnt[cur], cnt);
            s0 = s1 = cnt = 0.f; cur = s;
        }
        unsigned v = *(const unsigned*)(X + n * AST + c0);
        s0 += bf2f(v & 0xffffu);
        s1 += bf2f(v >> 16);
        cnt += 1.f;
    }
    atomicAdd(&frag_sum[(size_t)cur * 128 + c0], s0);
    atomicAdd(&frag_sum[(size_t)cur * 128 + c0 + 1], s1);
    if (lane == 0) atomicAdd(&frag_cnt[cur], cnt);
}

// ---------------------------------------------------------------------------
// fragment MLP + heads: one wave per 64-frag strip, zero barriers.
// Layer-1 A built on the fly from global (root_emb/frag_sum L2/L3-hot).
// ---------------------------------------------------------------------------
__global__ __launch_bounds__(256, 2)
void frag_kernel(const float* __restrict__ root_emb, const float* __restrict__ frag_sum,
                 const float* __restrict__ frag_cnt, const int* __restrict__ ind_maps,
                 const int* __restrict__ broken,
                 const unsigned short* __restrict__ WT_m1, const float* __restrict__ b_m1,
                 const unsigned short* __restrict__ WT_m2, const float* __restrict__ b_m2,
                 const unsigned short* __restrict__ WT_h,
                 const float* __restrict__ b_out, const float* __restrict__ b_attn,
                 float* __restrict__ out0, float* __restrict__ out1)
{
    __shared__ unsigned short abuf[4 * 64 * AST];   // 69632 B -> 2 blocks/CU
    const int tid = threadIdx.x, wv = tid >> 6, lane = tid & 63;
    const int strip = blockIdx.x * 4 + wv;
    const long f0 = (long)strip * 64;
    if (f0 >= 100000) return;
    unsigned short* X = abuf + wv * (64 * AST);
    const int col0 = lane & 15, q = lane >> 4;

    int rid[4]; float inv[4]; int bi[4];
#pragma unroll
    for (int mt = 0; mt < 4; ++mt) {
        int fc = (int)f0 + mt * 16 + col0; if (fc > 99999) fc = 99999;
        rid[mt] = ind_maps[fc];
        inv[mt] = 1.0f / fmaxf(frag_cnt[fc], 1.0f);
        int b = broken[fc]; bi[mt] = b < 0 ? 0 : (b > 12 ? 12 : b);
    }

    float4v acc[4][8];
#pragma unroll
    for (int t = 0; t < 8; ++t) {
        float b = b_m1[t * 16 + col0];
#pragma unroll
        for (int mt = 0; mt < 4; ++mt) acc[mt][t] = (float4v){b, b, b, b};
    }
    for (int ks = 0; ks < 416; ks += 32) {
        const int k0 = ks + q * 8;
        short8 B[8];
#pragma unroll
        for (int t = 0; t < 8; ++t)
            B[t] = *(const short8*)(WT_m1 + (size_t)(t * 16 + col0) * 416 + k0);
#pragma unroll
        for (int mt = 0; mt < 4; ++mt) {
            int fc = (int)f0 + mt * 16 + col0; if (fc > 99999) fc = 99999;
            float av[8];
            if (k0 >= 384) {
#pragma unroll
                for (int i = 0; i < 8; ++i) {
                    int k = k0 + i;
                    av[i] = (k < 397 && (k - 384) == bi[mt]) ? 1.0f : 0.0f;
                }
            } else if (k0 < 128) {
                const float4* e = (const float4*)(root_emb + (size_t)rid[mt] * 128 + k0);
                float4 e0 = e[0], e1 = e[1];
                av[0] = e0.x; av[1] = e0.y; av[2] = e0.z; av[3] = e0.w;
                av[4] = e1.x; av[5] = e1.y; av[6] = e1.z; av[7] = e1.w;
            } else if (k0 < 256) {
                int kk = k0 - 128;
                const float4* e = (const float4*)(root_emb + (size_t)rid[mt] * 128 + kk);
                const float4* s = (const float4*)(frag_sum + (size_t)fc * 128 + kk);
                float4 e0 = e[0], e1 = e[1], s0 = s[0], s1 = s[1];
                float iv = inv[mt];
                av[0] = e0.x - s0.x * iv; av[1] = e0.y - s0.y * iv;
                av[2] = e0.z - s0.z * iv; av[3] = e0.w - s0.w * iv;
                av[4] = e1.x - s1.x * iv; av[5] = e1.y - s1.y * iv;
                av[6] = e1.z - s1.z * iv; av[7] = e1.w - s1.w * iv;
            } else {
                int kk = k0 - 256;
                const float4* s = (const float4*)(frag_sum + (size_t)fc * 128 + kk);
                float4 s0 = s[0], s1 = s[1];
                float iv = inv[mt];
                av[0] = s0.x * iv; av[1] = s0.y * iv; av[2] = s0.z * iv; av[3] = s0.w * iv;
                av[4] = s1.x * iv; av[5] = s1.y * iv; av[6] = s1.z * iv; av[7] = s1.w * iv;
            }
            short8 A;
#pragma unroll
            for (int i = 0; i < 8; ++i) A[i] = (short)f2bf(av[i]);
#pragma unroll
            for (int t = 0; t < 8; ++t)
                acc[mt][t] = __builtin_amdgcn_mfma_f32_16x16x32_bf16(A, B[t], acc[mt][t], 0, 0, 0);
        }
    }
    storeh(acc, X, lane, true);             // h1
    layerN<128>(X, WT_m2, b_m2, lane, acc);
    storeh(acc, X, lane, true);             // h2

    // heads: 2 n-tiles (26 valid cols), K=128, B from global (L2-hot)
    float4v hacc[4][2];
#pragma unroll
    for (int t = 0; t < 2; ++t) {
        int cc = t * 16 + col0;
        float b = cc < 13 ? b_out[cc] : (cc < 26 ? b_attn[cc - 13] : 0.0f);
#pragma unroll
        for (int mt = 0; mt < 4; ++mt) hacc[mt][t] = (float4v){b, b, b, b};
    }
#pragma unroll
    for (int ks = 0; ks < 128; ks += 32) {
        const int k0 = ks + q * 8;
        short8 B2[2];
#pragma unroll
        for (int t = 0; t < 2; ++t)
            B2[t] = *(const short8*)(WT_h + (t * 16 + col0) * 128 + k0);
#pragma unroll
        for (int mt = 0; mt < 4; ++mt) {
            short8 A = *(const short8*)(X + (mt * 16 + col0) * AST + k0);
#pragma unroll
            for (int t = 0; t < 2; ++t)
                hacc[mt][t] = __builtin_amdgcn_mfma_f32_16x16x32_bf16(A, B2[t], hacc[mt][t], 0, 0, 0);
        }
    }
#pragma unroll
    for (int mt = 0; mt < 4; ++mt)
#pragma unroll
        for (int t = 0; t < 2; ++t)
#pragma unroll
            for (int r = 0; r < 4; ++r) {
                long ff = f0 + mt * 16 + q * 4 + r;
                int cc = t * 16 + col0;
                if (ff < 100000) {
                    float v = hacc[mt][t][r];
                    if (cc < 13)      out0[ff * 13 + cc] = 1.0f / (1.0f + expf(-v));
                    else if (cc < 26) out1[ff * 13 + cc - 13] = v;
                }
            }
}

extern "C" void kernel_launch(void* const* d_in, const int* in_sizes, int n_in,
                              void* d_out, int out_size, void* d_ws, size_t ws_size,
                              hipStream_t stream)
{
    const float* node_h    = (const float*)d_in[0];
    const int*   seg_ids   = (const int*)d_in[1];
    const float* root_repr = (const float*)d_in[2];
    const int*   ind_maps  = (const int*)d_in[3];
    const int*   broken    = (const int*)d_in[4];
    const float* W_root = (const float*)d_in[5];  const float* b_root = (const float*)d_in[6];
    const float* W_in   = (const float*)d_in[7];  const float* b_in   = (const float*)d_in[8];
    const float* W_g1   = (const float*)d_in[9];  const float* b_g1   = (const float*)d_in[10];
    const float* W_g2   = (const float*)d_in[11]; const float* b_g2   = (const float*)d_in[12];
    const float* W_m1   = (const float*)d_in[13]; const float* b_m1   = (const float*)d_in[14];
    const float* W_m2   = (const float*)d_in[15]; const float* b_m2   = (const float*)d_in[16];
    const float* W_out  = (const float*)d_in[17]; const float* b_out  = (const float*)d_in[18];
    const float* W_attn = (const float*)d_in[19]; const float* b_attn = (const float*)d_in[20];

    char* ws = (char*)d_ws;
    float* root_emb = (float*)ws;                          // 2000*128*4   = 1,024,000
    float* frag_sum = (float*)(ws + 1024000);              // 100000*128*4 = 51,200,000
    float* frag_cnt = (float*)(ws + 52224000);             // 100000*4     = 400,000
    unsigned short* wt = (unsigned short*)(ws + 52624000); // bf16 weights
    const unsigned short* WT_in = wt;
    const unsigned short* WT_g1 = wt + 12288;
    const unsigned short* WT_g2 = WT_g1 + 16384;
    const unsigned short* WT_m1 = WT_g2 + 16384;
    const unsigned short* WT_m2 = WT_m1 + 53248;
    const unsigned short* WT_h  = WT_m2 + 16384;

    hipMemsetAsync(frag_sum, 0, 51600000, stream);  // frag_sum + frag_cnt

    float* out0 = (float*)d_out;
    float* out1 = out0 + (size_t)100000 * 13;

    prep_kernel<<<464, 256, 0, stream>>>(W_in, W_g1, W_g2, W_m1, W_m2, W_out, W_attn, wt);
    root_kernel<<<2000, 128, 0, stream>>>(root_repr, W_root, b_root, root_emb);
    node_kernel<<<1563, 512, 0, stream>>>(node_h, seg_ids, WT_in, b_in,
                                          WT_g1, b_g1, WT_g2, b_g2, frag_sum, frag_cnt);
    frag_kernel<<<391, 256, 0, stream>>>(root_emb, frag_sum, frag_cnt, ind_maps, broken,
                                         WT_m1, b_m1, WT_m2, b_m2, WT_h, b_out, b_attn,
                                         out0, out1);
}

// Round 4
// 585.088 us; speedup vs baseline: 3.9750x; 1.1855x over previous
//
#include <hip/hip_runtime.h>
#include <math.h>

typedef __attribute__((ext_vector_type(8))) short short8;
typedef __attribute__((ext_vector_type(4))) float float4v;

#define AST 136   // activation row stride (bf16 elems) for 128-wide buffers
#define CST 424   // cat row stride (bf16 elems), 416 padded, 848B = 16B-aligned

__device__ __forceinline__ unsigned short f2bf(float f) {
    union { float f; unsigned u; } v; v.f = f;
    return (unsigned short)((v.u + 0x7fffu + ((v.u >> 16) & 1u)) >> 16);
}
__device__ __forceinline__ float bf2f(unsigned v) {
    union { unsigned u; float f; } x; x.u = v << 16; return x.f;
}

// ---------------------------------------------------------------------------
// N-split MFMA layer: block's 64-row A-tile in shared LDS (stride astr); this
// wave computes n-tiles tb,tb+1 (32 cols). 2 global B-loads per k-step.
// ---------------------------------------------------------------------------
template<int KP>
__device__ __forceinline__ void layer2t(const unsigned short* X, int astr,
                                        const unsigned short* __restrict__ WT,
                                        const float* __restrict__ bias,
                                        int lane, int tb, float4v acc[4][2])
{
    const int col0 = lane & 15, q = lane >> 4;
#pragma unroll
    for (int t = 0; t < 2; ++t) {
        float b = bias[(tb + t) * 16 + col0];
#pragma unroll
        for (int mt = 0; mt < 4; ++mt) acc[mt][t] = (float4v){b, b, b, b};
    }
#pragma unroll
    for (int ks = 0; ks < KP; ks += 32) {
        const int k0 = ks + q * 8;
        short8 B[2];
#pragma unroll
        for (int t = 0; t < 2; ++t)
            B[t] = *(const short8*)(WT + (size_t)((tb + t) * 16 + col0) * KP + k0);
#pragma unroll
        for (int mt = 0; mt < 4; ++mt) {
            short8 A = *(const short8*)(X + (mt * 16 + col0) * astr + k0);
#pragma unroll
            for (int t = 0; t < 2; ++t)
                acc[mt][t] = __builtin_amdgcn_mfma_f32_16x16x32_bf16(A, B[t], acc[mt][t], 0, 0, 0);
        }
    }
}

// C/D: col = (tb+t)*16+col0, row = mt*16 + q*4 + r
__device__ __forceinline__ void store2t(float4v acc[4][2], unsigned short* Y,
                                        int lane, int tb, bool relu)
{
    const int col0 = lane & 15, q = lane >> 4;
#pragma unroll
    for (int mt = 0; mt < 4; ++mt)
#pragma unroll
        for (int t = 0; t < 2; ++t)
#pragma unroll
            for (int r = 0; r < 4; ++r) {
                float v = acc[mt][t][r];
                if (relu) v = fmaxf(v, 0.0f);
                Y[(mt * 16 + q * 4 + r) * AST + (tb + t) * 16 + col0] = f2bf(v);
            }
}

// ---------------------------------------------------------------------------
// weight prep: fp32 [K][128] -> bf16 transposed [128][KP] (zero k-padding)
// ---------------------------------------------------------------------------
__global__ void prep_kernel(const float* __restrict__ W_in, const float* __restrict__ W_g1,
                            const float* __restrict__ W_g2, const float* __restrict__ W_m1,
                            const float* __restrict__ W_m2, const float* __restrict__ W_out,
                            const float* __restrict__ W_attn, unsigned short* __restrict__ wt)
{
    int i = blockIdx.x * 256 + threadIdx.x;
    unsigned short* WT_in = wt;                 // [128][96]
    unsigned short* WT_g1 = WT_in + 12288;      // [128][128]
    unsigned short* WT_g2 = WT_g1 + 16384;      // [128][128]
    unsigned short* WT_m1 = WT_g2 + 16384;      // [128][416]
    unsigned short* WT_m2 = WT_m1 + 53248;      // [128][128]
    unsigned short* WT_h  = WT_m2 + 16384;      // [32][128]
    if (i < 12288) { int n = i / 96, k = i - n * 96;
        WT_in[i] = (k < 86) ? f2bf(W_in[k * 128 + n]) : 0; return; }
    i -= 12288;
    if (i < 16384) { int n = i >> 7, k = i & 127;
        WT_g1[i] = f2bf(W_g1[k * 128 + n]); return; }
    i -= 16384;
    if (i < 16384) { int n = i >> 7, k = i & 127;
        WT_g2[i] = f2bf(W_g2[k * 128 + n]); return; }
    i -= 16384;
    if (i < 53248) { int n = i / 416, k = i - n * 416;
        WT_m1[i] = (k < 397) ? f2bf(W_m1[k * 128 + n]) : 0; return; }
    i -= 53248;
    if (i < 16384) { int n = i >> 7, k = i & 127;
        WT_m2[i] = f2bf(W_m2[k * 128 + n]); return; }
    i -= 16384;
    if (i < 4096) { int n = i >> 7, k = i & 127;
        WT_h[i] = (n < 13) ? f2bf(W_out[k * 13 + n])
                           : (n < 26 ? f2bf(W_attn[k * 13 + (n - 13)]) : 0); }
}

// ---------------------------------------------------------------------------
// root encoder (fp32, tiny)
// ---------------------------------------------------------------------------
__global__ void root_kernel(const float* __restrict__ root_repr,
                            const float* __restrict__ W_root,
                            const float* __restrict__ b_root,
                            float* __restrict__ root_emb)
{
    __shared__ float x[86];
    const int r = blockIdx.x, tid = threadIdx.x;  // 128
    if (tid < 86) x[tid] = root_repr[(size_t)r * 86 + tid];
    __syncthreads();
    float acc = b_root[tid];
    for (int k = 0; k < 86; ++k)
        acc = fmaf(x[k], W_root[k * 128 + tid], acc);
    root_emb[(size_t)r * 128 + tid] = fmaxf(acc, 0.0f);
}

// ---------------------------------------------------------------------------
// node pipeline: 1 block = 1 strip of 64 nodes; 4 waves, each owns 2 n-tiles.
// X/Y ping-pong in LDS (34.8 KB/block -> 4 blocks/CU = 16 waves/CU).
// Segment reduction: interior runs = plain stores, boundary runs = atomics.
// ---------------------------------------------------------------------------
__global__ __launch_bounds__(256, 4)
void node_kernel(const float* __restrict__ node_h, const int* __restrict__ seg_ids,
                 const unsigned short* __restrict__ WT_in, const float* __restrict__ b_in,
                 const unsigned short* __restrict__ WT_g1, const float* __restrict__ b_g1,
                 const unsigned short* __restrict__ WT_g2, const float* __restrict__ b_g2,
                 float* __restrict__ frag_sum, float* __restrict__ frag_cnt)
{
    __shared__ __align__(16) unsigned short X[64 * AST];
    __shared__ __align__(16) unsigned short Y[64 * AST];
    __shared__ int segs[64];
    const int tid = threadIdx.x, wv = tid >> 6, lane = tid & 63, tb = wv * 2;
    const long n0 = (long)blockIdx.x * 64;

    if (tid < 64) segs[tid] = seg_ids[n0 + tid];
    // stage x: 64 rows x 86 fp32 (contiguous 1376 float4) -> bf16 LDS
    {
        const float4* src = (const float4*)(node_h + n0 * 86);
#pragma unroll
        for (int j = 0; j < 6; ++j) {
            int i4 = j * 256 + tid;
            if (i4 < 1376) {
                float4 v = src[i4];
                int e = i4 << 2;
                int n = e / 86, k = e - n * 86;
                X[n * AST + k] = f2bf(v.x);
                int e1 = e + 1; n = e1 / 86; k = e1 - n * 86; X[n * AST + k] = f2bf(v.y);
                int e2 = e + 2; n = e2 / 86; k = e2 - n * 86; X[n * AST + k] = f2bf(v.z);
                int e3 = e + 3; n = e3 / 86; k = e3 - n * 86; X[n * AST + k] = f2bf(v.w);
            }
        }
        for (int idx = tid; idx < 640; idx += 256) {
            int n = idx / 10, k = idx - n * 10;
            X[n * AST + 86 + k] = 0;
        }
    }
    __syncthreads();

    float4v acc[4][2];
    layer2t<96>(X, AST, WT_in, b_in, lane, tb, acc);
    store2t(acc, Y, lane, tb, false);          // layer 1: NO relu
    __syncthreads();
    layer2t<128>(Y, AST, WT_g1, b_g1, lane, tb, acc);
    store2t(acc, X, lane, tb, true);
    __syncthreads();
    layer2t<128>(X, AST, WT_g2, b_g2, lane, tb, acc);
    store2t(acc, Y, lane, tb, true);           // h3 in Y
    __syncthreads();

    // reduction: thread (col = tid&127, half = tid>>7) scans 32 rows
    {
        const int col = tid & 127, half = tid >> 7, r0 = half << 5;
        const int prevSeg = (half == 1) ? segs[31] : -1;
        const int nextSeg = (half == 0) ? segs[32] : -1;
        int cur = segs[r0], runStart = r0;
        float sum = 0.f, cnt = 0.f;
        for (int n = r0; n < r0 + 32; ++n) {
            int s = segs[n];
            if (s != cur) {
                bool bnd = (runStart == r0) && (half == 0 || prevSeg == cur);
                if (bnd) atomicAdd(&frag_sum[(size_t)cur * 128 + col], sum);
                else     frag_sum[(size_t)cur * 128 + col] = sum;
                if (col == 0) {
                    if (bnd) atomicAdd(&frag_cnt[cur], cnt);
                    else     frag_cnt[cur] = cnt;
                }
                sum = 0.f; cnt = 0.f; cur = s; runStart = n;
            }
            sum += bf2f((unsigned)Y[n * AST + col]);
            cnt += 1.f;
        }
        bool bnd = ((runStart == r0) && (half == 0 || prevSeg == cur))
                   || (half == 1) || (nextSeg == cur);
        if (bnd) atomicAdd(&frag_sum[(size_t)cur * 128 + col], sum);
        else     frag_sum[(size_t)cur * 128 + col] = sum;
        if (col == 0) {
            if (bnd) atomicAdd(&frag_cnt[cur], cnt);
            else     frag_cnt[cur] = cnt;
        }
    }
}

// ---------------------------------------------------------------------------
// fragment MLP + heads: 1 block = 64 frags; cat staged in LDS, N-split waves.
// ---------------------------------------------------------------------------
__global__ __launch_bounds__(256, 2)
void frag_kernel(const float* __restrict__ root_emb, const float* __restrict__ frag_sum,
                 const float* __restrict__ frag_cnt, const int* __restrict__ ind_maps,
                 const int* __restrict__ broken,
                 const unsigned short* __restrict__ WT_m1, const float* __restrict__ b_m1,
                 const unsigned short* __restrict__ WT_m2, const float* __restrict__ b_m2,
                 const unsigned short* __restrict__ WT_h,
                 const float* __restrict__ b_out, const float* __restrict__ b_attn,
                 float* __restrict__ out0, float* __restrict__ out1)
{
    __shared__ __align__(16) unsigned short cat[64 * CST];   // 54,272 B
    __shared__ __align__(16) unsigned short Y[64 * AST];     // 17,408 B
    unsigned short* X2 = cat;                                // h2 reuses cat
    const int tid = threadIdx.x, wv = tid >> 6, lane = tid & 63, tb = wv * 2;
    const int col0 = lane & 15, q = lane >> 4;
    const long f0 = (long)blockIdx.x * 64;

    // build cat: row m = tid>>2, thread j = tid&3 covers k in [32j, 32j+32)
    {
        const int m = tid >> 2, j = tid & 3;
        int fc = (int)f0 + m; if (fc > 99999) fc = 99999;
        const int rid = ind_maps[fc];
        const float inv = 1.0f / fmaxf(frag_cnt[fc], 1.0f);
        unsigned short* row = cat + m * CST;
#pragma unroll
        for (int jj = 0; jj < 8; ++jj) {
            int k = j * 32 + jj * 4;
            float4 e = *(const float4*)(root_emb + (size_t)rid * 128 + k);
            float4 s = *(const float4*)(frag_sum + (size_t)fc * 128 + k);
            float sx = s.x * inv, sy = s.y * inv, sz = s.z * inv, sw = s.w * inv;
            row[k]     = f2bf(e.x); row[k + 1] = f2bf(e.y);
            row[k + 2] = f2bf(e.z); row[k + 3] = f2bf(e.w);
            row[128 + k]     = f2bf(e.x - sx); row[128 + k + 1] = f2bf(e.y - sy);
            row[128 + k + 2] = f2bf(e.z - sz); row[128 + k + 3] = f2bf(e.w - sw);
            row[256 + k]     = f2bf(sx); row[256 + k + 1] = f2bf(sy);
            row[256 + k + 2] = f2bf(sz); row[256 + k + 3] = f2bf(sw);
        }
        if (j == 3) {
            int b = broken[fc]; b = b < 0 ? 0 : (b > 12 ? 12 : b);
            for (int kk = 0; kk < 32; ++kk)
                row[384 + kk] = (kk == b) ? 0x3f80 : 0;   // bf16 1.0
        }
    }
    __syncthreads();

    float4v acc[4][2];
    layer2t<416>(cat, CST, WT_m1, b_m1, lane, tb, acc);
    store2t(acc, Y, lane, tb, true);           // h1
    __syncthreads();
    layer2t<128>(Y, AST, WT_m2, b_m2, lane, tb, acc);
    store2t(acc, X2, lane, tb, true);          // h2 (overwrites cat area)
    __syncthreads();

    // heads: wave w handles m-tile w, both n-tiles (26 valid cols), K=128
    float4v hacc[2];
#pragma unroll
    for (int t = 0; t < 2; ++t) {
        int cc = t * 16 + col0;
        float b = cc < 13 ? b_out[cc] : (cc < 26 ? b_attn[cc - 13] : 0.0f);
        hacc[t] = (float4v){b, b, b, b};
    }
#pragma unroll
    for (int ks = 0; ks < 128; ks += 32) {
        const int k0 = ks + q * 8;
        short8 A = *(const short8*)(X2 + (wv * 16 + col0) * AST + k0);
#pragma unroll
        for (int t = 0; t < 2; ++t) {
            short8 B = *(const short8*)(WT_h + (t * 16 + col0) * 128 + k0);
            hacc[t] = __builtin_amdgcn_mfma_f32_16x16x32_bf16(A, B, hacc[t], 0, 0, 0);
        }
    }
#pragma unroll
    for (int t = 0; t < 2; ++t)
#pragma unroll
        for (int r = 0; r < 4; ++r) {
            long ff = f0 + wv * 16 + q * 4 + r;
            int cc = t * 16 + col0;
            if (ff < 100000) {
                float v = hacc[t][r];
                if (cc < 13)      out0[ff * 13 + cc] = 1.0f / (1.0f + expf(-v));
                else if (cc < 26) out1[ff * 13 + cc - 13] = v;
            }
        }
}

extern "C" void kernel_launch(void* const* d_in, const int* in_sizes, int n_in,
                              void* d_out, int out_size, void* d_ws, size_t ws_size,
                              hipStream_t stream)
{
    const float* node_h    = (const float*)d_in[0];
    const int*   seg_ids   = (const int*)d_in[1];
    const float* root_repr = (const float*)d_in[2];
    const int*   ind_maps  = (const int*)d_in[3];
    const int*   broken    = (const int*)d_in[4];
    const float* W_root = (const float*)d_in[5];  const float* b_root = (const float*)d_in[6];
    const float* W_in   = (const float*)d_in[7];  const float* b_in   = (const float*)d_in[8];
    const float* W_g1   = (const float*)d_in[9];  const float* b_g1   = (const float*)d_in[10];
    const float* W_g2   = (const float*)d_in[11]; const float* b_g2   = (const float*)d_in[12];
    const float* W_m1   = (const float*)d_in[13]; const float* b_m1   = (const float*)d_in[14];
    const float* W_m2   = (const float*)d_in[15]; const float* b_m2   = (const float*)d_in[16];
    const float* W_out  = (const float*)d_in[17]; const float* b_out  = (const float*)d_in[18];
    const float* W_attn = (const float*)d_in[19]; const float* b_attn = (const float*)d_in[20];

    char* ws = (char*)d_ws;
    float* root_emb = (float*)ws;                          // 2000*128*4
    float* frag_sum = (float*)(ws + 1024000);              // 100000*128*4
    float* frag_cnt = (float*)(ws + 52224000);             // 100000*4
    unsigned short* wt = (unsigned short*)(ws + 52624000); // bf16 weights
    const unsigned short* WT_in = wt;
    const unsigned short* WT_g1 = wt + 12288;
    const unsigned short* WT_g2 = WT_g1 + 16384;
    const unsigned short* WT_m1 = WT_g2 + 16384;
    const unsigned short* WT_m2 = WT_m1 + 53248;
    const unsigned short* WT_h  = WT_m2 + 16384;

    hipMemsetAsync(frag_sum, 0, 51600000, stream);  // frag_sum + frag_cnt

    float* out0 = (float*)d_out;
    float* out1 = out0 + (size_t)100000 * 13;

    prep_kernel<<<464, 256, 0, stream>>>(W_in, W_g1, W_g2, W_m1, W_m2, W_out, W_attn, wt);
    root_kernel<<<2000, 128, 0, stream>>>(root_repr, W_root, b_root, root_emb);
    node_kernel<<<12500, 256, 0, stream>>>(node_h, seg_ids, WT_in, b_in,
                                           WT_g1, b_g1, WT_g2, b_g2, frag_sum, frag_cnt);
    frag_kernel<<<1563, 256, 0, stream>>>(root_emb, frag_sum, frag_cnt, ind_maps, broken,
                                          WT_m1, b_m1, WT_m2, b_m2, WT_h, b_out, b_attn,
                                          out0, out1);
}